// Round 6
// baseline (1024.518 us; speedup 1.0000x reference)
//
#include <hip/hip_runtime.h>

#define DD 256
#define BB 32
#define NN 8192
#define CC 1000
#define SUBS 32            // blocks per batch in k_main (each block: 256 rows)
#define PPASS 8            // passes per probe kernel (surfacing: 8*~50us > 160us fills)

typedef float f4 __attribute__((ext_vector_type(4)));

// DPP row_ror add: s += rotate_within_16(s, n). CTRL = 0x120|n (row_ror:n).
template <int CTRL>
__device__ __forceinline__ float dpp_ror_add(float s) {
    int r = __builtin_amdgcn_update_dpp(0, __float_as_int(s), CTRL, 0xF, 0xF, true);
    return s + __int_as_float(r);
}
// All-reduce sum across each aligned 16-lane group, result in every lane.
__device__ __forceinline__ float rowsum16(float s) {
    s = dpp_ror_add<0x121>(s);  // row_ror:1
    s = dpp_ror_add<0x122>(s);  // row_ror:2
    s = dpp_ror_add<0x124>(s);  // row_ror:4
    s = dpp_ror_add<0x128>(s);  // row_ror:8
    return s;
}

// ---------------------------------------------------------------------------
// k_prep: 32 blocks (one per batch b).
// ---------------------------------------------------------------------------
__global__ __launch_bounds__(256) void k_prep(const float* __restrict__ W,
                                              const float* __restrict__ A,
                                              const float* __restrict__ obj,
                                              float* __restrict__ v1,
                                              float* __restrict__ c) {
    int b = blockIdx.x, t = threadIdx.x;
    int q  = t >> 6;
    int cs = (t & 63) * 4;
    __shared__ float s1[4][DD], s2[4][DD];
    __shared__ float sc[4];
    f4 a1 = {0.f, 0.f, 0.f, 0.f}, a2 = a1;
#pragma unroll 8
    for (int k = q; k < DD; k += 4) {
        f4 w = *(const f4*)(W + (size_t)k * DD + cs);
        a1 += A[k] * w;
        a2 += A[DD + k] * w;
    }
    *(f4*)&s1[q][cs] = a1;
    *(f4*)&s2[q][cs] = a2;
    __syncthreads();
    float vv1 = s1[0][t] + s1[1][t] + s1[2][t] + s1[3][t];
    float vv2 = s2[0][t] + s2[1][t] + s2[2][t] + s2[3][t];
    if (b == 0) v1[t] = vv1;
    float p = vv2 * obj[(size_t)b * DD + t];
    p = rowsum16(p);
    p += __shfl_xor(p, 16, 64);
    p += __shfl_xor(p, 32, 64);
    if ((t & 63) == 0) sc[t >> 6] = p;
    __syncthreads();
    if (t == 0) c[b] = sc[0] + sc[1] + sc[2] + sc[3];
}

// ---------------------------------------------------------------------------
// k_main: unchanged from R5 (68.5 us config).
// ---------------------------------------------------------------------------
__global__ __launch_bounds__(256, 4) void k_main(const float* __restrict__ atom,
                                                 const float* __restrict__ v1,
                                                 const float* __restrict__ c,
                                                 float* __restrict__ partials) {
    int blk  = blockIdx.x;
    int b    = blk >> 5;
    int sub  = blk & 31;
    int tid  = threadIdx.x;
    int wave = tid >> 6, lane = tid & 63;
    int grp  = lane >> 4, gl = lane & 15;

    __shared__ float sv1[DD];
    __shared__ float tsh[4][DD];
    sv1[tid] = v1[tid];
    __syncthreads();
    float4 w0 = *(const float4*)&sv1[gl * 4];
    float4 w1 = *(const float4*)&sv1[gl * 4 + 64];
    float4 w2 = *(const float4*)&sv1[gl * 4 + 128];
    float4 w3 = *(const float4*)&sv1[gl * 4 + 192];
    float  cb = c[b];

    const float* p = atom + ((size_t)b * NN + (size_t)sub * 256 + wave * 64 + grp) * DD
                   + gl * 4;

    f4 A0 = {0.f, 0.f, 0.f, 0.f}, A1 = A0, A2 = A0, A3 = A0;

#pragma unroll 4
    for (int g = 0; g < 16; ++g) {
        f4 x0 = *(const f4*)(p);
        f4 x1 = *(const f4*)(p + 64);
        f4 x2 = *(const f4*)(p + 128);
        f4 x3 = *(const f4*)(p + 192);
        p += 4 * DD;
        float dot = x0.x * w0.x + x0.y * w0.y + x0.z * w0.z + x0.w * w0.w
                  + x1.x * w1.x + x1.y * w1.y + x1.z * w1.z + x1.w * w1.w
                  + x2.x * w2.x + x2.y * w2.y + x2.z * w2.z + x2.w * w2.w
                  + x3.x * w3.x + x3.y * w3.y + x3.z * w3.z + x3.w * w3.w;
        float att = rowsum16(dot) + cb;
        A0 += att * x0;
        A1 += att * x1;
        A2 += att * x2;
        A3 += att * x3;
    }

#define XRED(v)                              \
    v.x += __shfl_xor(v.x, 16, 64); v.x += __shfl_xor(v.x, 32, 64); \
    v.y += __shfl_xor(v.y, 16, 64); v.y += __shfl_xor(v.y, 32, 64); \
    v.z += __shfl_xor(v.z, 16, 64); v.z += __shfl_xor(v.z, 32, 64); \
    v.w += __shfl_xor(v.w, 16, 64); v.w += __shfl_xor(v.w, 32, 64);
    XRED(A0) XRED(A1) XRED(A2) XRED(A3)
#undef XRED

    if (grp == 0) {
        *(f4*)&tsh[wave][gl * 4]       = A0;
        *(f4*)&tsh[wave][gl * 4 + 64]  = A1;
        *(f4*)&tsh[wave][gl * 4 + 128] = A2;
        *(f4*)&tsh[wave][gl * 4 + 192] = A3;
    }
    __syncthreads();
    partials[(size_t)blk * DD + tid] =
        tsh[0][tid] + tsh[1][tid] + tsh[2][tid] + tsh[3][tid];
}

// ---------------------------------------------------------------------------
// k_mid / k_class: unchanged from R5.
// ---------------------------------------------------------------------------
__global__ __launch_bounds__(256) void k_mid(const float* __restrict__ partials,
                                             const float* __restrict__ W,
                                             const float* __restrict__ obj,
                                             float* __restrict__ x) {
    int b = blockIdx.x >> 4, q = blockIdx.x & 15;
    int t = threadIdx.x;
    __shared__ float tt[DD];
    __shared__ float so[DD];

    float s = 0.f;
#pragma unroll 8
    for (int i = 0; i < SUBS; ++i) s += partials[((size_t)(b * SUBS + i)) * DD + t];
    tt[t] = s;
    so[t] = obj[(size_t)b * DD + t];
    __syncthreads();

    int kk = t >> 4, cs = t & 15;
    int k  = q * 16 + kk;
    const float4* wr = (const float4*)(W + (size_t)k * DD + cs * 16);
    float p = 0.f, po = 0.f;
#pragma unroll
    for (int ii = 0; ii < 4; ++ii) {
        int i = (ii + cs) & 3;
        float4 a  = wr[i];
        float4 xx = *(const float4*)&tt[cs * 16 + i * 4];
        float4 oo = *(const float4*)&so[cs * 16 + i * 4];
        p  += a.x * xx.x + a.y * xx.y + a.z * xx.z + a.w * xx.w;
        po += a.x * oo.x + a.y * oo.y + a.z * oo.z + a.w * oo.w;
    }
    p  = rowsum16(p);
    po = rowsum16(po);
    if (cs == 0) {
        x[b * 2 * DD + DD + k] = p;   // msg
        x[b * 2 * DD + k]      = po;  // o1
    }
}

__global__ __launch_bounds__(256) void k_class(const float* __restrict__ x,
                                               const float* __restrict__ CW,
                                               const float* __restrict__ CB,
                                               float* __restrict__ out) {
    int bg = blockIdx.x / 63, ch = blockIdx.x % 63;
    int t = threadIdx.x;
    __shared__ float xs[8][2 * DD];   // 16 KB

    {
        const f4* src = (const f4*)(x + (size_t)bg * 8 * 2 * DD);
        f4* dst = (f4*)&xs[0][0];
#pragma unroll
        for (int i = 0; i < 4; ++i) dst[t + 256 * i] = src[t + 256 * i];
    }
    __syncthreads();

    int cl = t >> 4, seg = t & 15;
    int j = ch * 16 + cl;
    if (j < CC) {
        const f4* cw = (const f4*)(CW + (size_t)j * 2 * DD + seg * 32);
        float p[8];
#pragma unroll
        for (int bb = 0; bb < 8; ++bb) p[bb] = 0.f;
#pragma unroll
        for (int ii = 0; ii < 8; ++ii) {
            int i = (ii + seg) & 7;
            f4 a = cw[i];
#pragma unroll
            for (int bb = 0; bb < 8; ++bb) {
                f4 v = *(const f4*)&xs[bb][seg * 32 + i * 4];
                p[bb] += a.x * v.x + a.y * v.y + a.z * v.z + a.w * v.w;
            }
        }
#pragma unroll
        for (int bb = 0; bb < 8; ++bb) p[bb] = rowsum16(p[bb]);
        if (seg == 0) {
            float cb = CB[j];
            int b0 = bg * 8;
#pragma unroll
            for (int bb = 0; bb < 8; ++bb)
                out[(size_t)(b0 + bb) * CC + j] = p[bb] + cb;
        }
    }
}

// ===========================================================================
// PROBES (instrumentation round): each >=160us so they surface in rocprof
// top-5 with FETCH_SIZE / VALUBusy / Occupancy. Pass-loop is unroll-1 with
// per-pass address rotation (defeats cross-pass CSE); accumulators carried
// across passes (defeats DCE); single scratch write keeps everything live.
// ===========================================================================

// probeA: exact k_main inner loop, x PPASS.  dur/8 = steady-state k_main.
__global__ __launch_bounds__(256, 4) void k_probeA(const float* __restrict__ atom,
                                                   const float* __restrict__ v1,
                                                   const float* __restrict__ c,
                                                   float* __restrict__ scr) {
    int blk  = blockIdx.x;
    int b    = blk >> 5;
    int sub  = blk & 31;
    int tid  = threadIdx.x;
    int wave = tid >> 6, lane = tid & 63;
    int grp  = lane >> 4, gl = lane & 15;

    __shared__ float sv1[DD];
    sv1[tid] = v1[tid];
    __syncthreads();
    float4 w0 = *(const float4*)&sv1[gl * 4];
    float4 w1 = *(const float4*)&sv1[gl * 4 + 64];
    float4 w2 = *(const float4*)&sv1[gl * 4 + 128];
    float4 w3 = *(const float4*)&sv1[gl * 4 + 192];
    float  cb = c[b];

    f4 A0 = {0.f, 0.f, 0.f, 0.f}, A1 = A0, A2 = A0, A3 = A0;

#pragma unroll 1
    for (int pp = 0; pp < PPASS; ++pp) {
        int esub = (sub + pp) & 31;    // rotate slice: same global coverage, no CSE
        const float* p = atom + ((size_t)b * NN + (size_t)esub * 256 + wave * 64 + grp) * DD
                       + gl * 4;
#pragma unroll 4
        for (int g = 0; g < 16; ++g) {
            f4 x0 = *(const f4*)(p);
            f4 x1 = *(const f4*)(p + 64);
            f4 x2 = *(const f4*)(p + 128);
            f4 x3 = *(const f4*)(p + 192);
            p += 4 * DD;
            float dot = x0.x * w0.x + x0.y * w0.y + x0.z * w0.z + x0.w * w0.w
                      + x1.x * w1.x + x1.y * w1.y + x1.z * w1.z + x1.w * w1.w
                      + x2.x * w2.x + x2.y * w2.y + x2.z * w2.z + x2.w * w2.w
                      + x3.x * w3.x + x3.y * w3.y + x3.z * w3.z + x3.w * w3.w;
            float att = rowsum16(dot) + cb;
            A0 += att * x0;
            A1 += att * x1;
            A2 += att * x2;
            A3 += att * x3;
        }
    }
    scr[(size_t)blk * 256 + tid] =
        A0.x + A0.y + A0.z + A0.w + A1.x + A1.y + A1.z + A1.w +
        A2.x + A2.y + A2.z + A2.w + A3.x + A3.y + A3.z + A3.w;
}

// probeB: same load mapping, attention math stripped (pure read+add).
// A - B isolates compute/dependency stalls in the k_main loop.
__global__ __launch_bounds__(256, 4) void k_probeB(const float* __restrict__ atom,
                                                   float* __restrict__ scr) {
    int blk  = blockIdx.x;
    int b    = blk >> 5;
    int sub  = blk & 31;
    int tid  = threadIdx.x;
    int wave = tid >> 6, lane = tid & 63;
    int grp  = lane >> 4, gl = lane & 15;

    f4 A0 = {0.f, 0.f, 0.f, 0.f}, A1 = A0, A2 = A0, A3 = A0;

#pragma unroll 1
    for (int pp = 0; pp < PPASS; ++pp) {
        int esub = (sub + pp) & 31;
        const float* p = atom + ((size_t)b * NN + (size_t)esub * 256 + wave * 64 + grp) * DD
                       + gl * 4;
#pragma unroll 4
        for (int g = 0; g < 16; ++g) {
            A0 += *(const f4*)(p);
            A1 += *(const f4*)(p + 64);
            A2 += *(const f4*)(p + 128);
            A3 += *(const f4*)(p + 192);
            p += 4 * DD;
        }
    }
    scr[(size_t)blk * 256 + tid] =
        A0.x + A0.y + A0.z + A0.w + A1.x + A1.y + A1.z + A1.w +
        A2.x + A2.y + A2.z + A2.w + A3.x + A3.y + A3.z + A3.w;
}

// probeC: canonical grid-stride f4 stream = achievable-read ceiling for this
// chip + steady cache state.  B - C isolates the k_main address mapping.
__global__ __launch_bounds__(256) void k_probeC(const float* __restrict__ atom,
                                                float* __restrict__ scr) {
    const size_t NT = (size_t)BB * SUBS * 256;          // 262144 threads
    size_t t = (size_t)blockIdx.x * 256 + threadIdx.x;
    f4 s = {0.f, 0.f, 0.f, 0.f};
#pragma unroll 1
    for (int pp = 0; pp < PPASS; ++pp) {
#pragma unroll 8
        for (int i = 0; i < 64; ++i) {
            size_t idx = t + (size_t)((i + pp * 8) & 63) * NT;  // bijective per pass
            s += *(const f4*)(atom + 4 * idx);
        }
    }
    scr[t] = s.x + s.y + s.z + s.w;
}

// ---------------------------------------------------------------------------
extern "C" void kernel_launch(void* const* d_in, const int* in_sizes, int n_in,
                              void* d_out, int out_size, void* d_ws, size_t ws_size,
                              hipStream_t stream) {
    const float* atom = (const float*)d_in[0];
    const float* obj  = (const float*)d_in[1];
    const float* W    = (const float*)d_in[2];
    const float* A    = (const float*)d_in[3];
    const float* CW   = (const float*)d_in[4];
    const float* CB   = (const float*)d_in[5];
    float* out = (float*)d_out;

    float* ws = (float*)d_ws;
    float* v1       = ws;                        // 256
    float* c        = ws + 256;                  // 32
    float* x        = ws + 512;                  // 32*512
    float* partials = x + (size_t)BB * 2 * DD;   // 1024*256 (~1 MB)
    float* scrA     = partials + (size_t)BB * SUBS * DD;   // 262144 each
    float* scrB     = scrA + (size_t)BB * SUBS * 256;
    float* scrC     = scrB + (size_t)BB * SUBS * 256;

    // real pipeline (identical to R5, 68.5 us)
    hipLaunchKernelGGL(k_prep,  dim3(BB),        dim3(256), 0, stream, W, A, obj, v1, c);
    hipLaunchKernelGGL(k_main,  dim3(BB * SUBS), dim3(256), 0, stream, atom, v1, c, partials);
    hipLaunchKernelGGL(k_mid,   dim3(BB * 16),   dim3(256), 0, stream, partials, W, obj, x);
    hipLaunchKernelGGL(k_class, dim3(4 * 63),    dim3(256), 0, stream, x, CW, CB, out);

    // instrumentation probes (this round only; removed next round)
    hipLaunchKernelGGL(k_probeA, dim3(BB * SUBS), dim3(256), 0, stream, atom, v1, c, scrA);
    hipLaunchKernelGGL(k_probeB, dim3(BB * SUBS), dim3(256), 0, stream, atom, scrB);
    hipLaunchKernelGGL(k_probeC, dim3(BB * SUBS), dim3(256), 0, stream, atom, scrC);
}

// Round 7
// 66.652 us; speedup vs baseline: 15.3711x; 15.3711x over previous
//
#include <hip/hip_runtime.h>

#define DD 256
#define BB 32
#define NN 8192
#define CC 1000
#define SUBS 32            // blocks per batch in k_main (each block: 256 rows)
#define CACHED_B 16        // batches b < CACHED_B use plain (L3-allocating) loads;
                           // b >= CACHED_B use NT loads (stream, don't evict).
                           // 16*8192*256*4B = 134 MB pinned half < 256 MB L3.

typedef float f4 __attribute__((ext_vector_type(4)));

__device__ __forceinline__ f4 ntload(const float* p) {
    return __builtin_nontemporal_load((const f4*)p);
}

// DPP row_ror add: s += rotate_within_16(s, n). CTRL = 0x120|n (row_ror:n).
template <int CTRL>
__device__ __forceinline__ float dpp_ror_add(float s) {
    int r = __builtin_amdgcn_update_dpp(0, __float_as_int(s), CTRL, 0xF, 0xF, true);
    return s + __int_as_float(r);
}
// All-reduce sum across each aligned 16-lane group, result in every lane.
__device__ __forceinline__ float rowsum16(float s) {
    s = dpp_ror_add<0x121>(s);  // row_ror:1
    s = dpp_ror_add<0x122>(s);  // row_ror:2
    s = dpp_ror_add<0x124>(s);  // row_ror:4
    s = dpp_ror_add<0x128>(s);  // row_ror:8
    return s;
}

// ---------------------------------------------------------------------------
// k_prep: 32 blocks (one per batch b).
//   v1[d] = sum_k A1[k] W[k,d]   (written by block 0)
//   c[b]  = sum_d obj[b,d] * (sum_k A2[k] W[k,d])
// ---------------------------------------------------------------------------
__global__ __launch_bounds__(256) void k_prep(const float* __restrict__ W,
                                              const float* __restrict__ A,
                                              const float* __restrict__ obj,
                                              float* __restrict__ v1,
                                              float* __restrict__ c) {
    int b = blockIdx.x, t = threadIdx.x;
    int q  = t >> 6;
    int cs = (t & 63) * 4;
    __shared__ float s1[4][DD], s2[4][DD];
    __shared__ float sc[4];
    f4 a1 = {0.f, 0.f, 0.f, 0.f}, a2 = a1;
#pragma unroll 8
    for (int k = q; k < DD; k += 4) {
        f4 w = *(const f4*)(W + (size_t)k * DD + cs);
        a1 += A[k] * w;
        a2 += A[DD + k] * w;
    }
    *(f4*)&s1[q][cs] = a1;
    *(f4*)&s2[q][cs] = a2;
    __syncthreads();
    float vv1 = s1[0][t] + s1[1][t] + s1[2][t] + s1[3][t];
    float vv2 = s2[0][t] + s2[1][t] + s2[2][t] + s2[3][t];
    if (b == 0) v1[t] = vv1;
    float p = vv2 * obj[(size_t)b * DD + t];
    p = rowsum16(p);
    p += __shfl_xor(p, 16, 64);
    p += __shfl_xor(p, 32, 64);
    if ((t & 63) == 0) sc[t >> 6] = p;
    __syncthreads();
    if (t == 0) c[b] = sc[0] + sc[1] + sc[2] + sc[3];
}

// ---------------------------------------------------------------------------
// k_main: the 268 MB atom pass, L3-PARTITIONED (R6 probe evidence):
//   probeC showed steady-state reads run at only 3 TB/s HBM-side because an
//   UNCONTROLLED 50% of atom is L3-resident (random miss pattern fragments
//   the HBM stream; FETCH == pass_time * 3 TB/s exactly).
//   Fix: deterministic partition. b < 16 -> plain loads (134 MB, becomes the
//   only L3-allocating atom traffic -> converges to resident, L3-speed).
//   b >= 16 -> NT loads (stream from HBM, no L3 allocation, no eviction of
//   the pinned half). Halves run concurrently in one kernel (block-uniform
//   branch; separate launches would serialize on the stream).
// ---------------------------------------------------------------------------
template <bool NT>
__device__ __forceinline__ void atom_loop(const float* __restrict__ p,
                                          const float4& w0, const float4& w1,
                                          const float4& w2, const float4& w3,
                                          float cb,
                                          f4& A0, f4& A1, f4& A2, f4& A3) {
#pragma unroll 4
    for (int g = 0; g < 16; ++g) {
        f4 x0 = NT ? ntload(p)       : *(const f4*)(p);
        f4 x1 = NT ? ntload(p + 64)  : *(const f4*)(p + 64);
        f4 x2 = NT ? ntload(p + 128) : *(const f4*)(p + 128);
        f4 x3 = NT ? ntload(p + 192) : *(const f4*)(p + 192);
        p += 4 * DD;
        float dot = x0.x * w0.x + x0.y * w0.y + x0.z * w0.z + x0.w * w0.w
                  + x1.x * w1.x + x1.y * w1.y + x1.z * w1.z + x1.w * w1.w
                  + x2.x * w2.x + x2.y * w2.y + x2.z * w2.z + x2.w * w2.w
                  + x3.x * w3.x + x3.y * w3.y + x3.z * w3.z + x3.w * w3.w;
        float att = rowsum16(dot) + cb;
        A0 += att * x0;
        A1 += att * x1;
        A2 += att * x2;
        A3 += att * x3;
    }
}

__global__ __launch_bounds__(256, 4) void k_main(const float* __restrict__ atom,
                                                 const float* __restrict__ v1,
                                                 const float* __restrict__ c,
                                                 float* __restrict__ partials) {
    int blk  = blockIdx.x;
    int b    = blk >> 5;
    int sub  = blk & 31;
    int tid  = threadIdx.x;
    int wave = tid >> 6, lane = tid & 63;
    int grp  = lane >> 4, gl = lane & 15;

    __shared__ float sv1[DD];
    __shared__ float tsh[4][DD];
    sv1[tid] = v1[tid];
    __syncthreads();
    float4 w0 = *(const float4*)&sv1[gl * 4];
    float4 w1 = *(const float4*)&sv1[gl * 4 + 64];
    float4 w2 = *(const float4*)&sv1[gl * 4 + 128];
    float4 w3 = *(const float4*)&sv1[gl * 4 + 192];
    float  cb = c[b];

    const float* p = atom + ((size_t)b * NN + (size_t)sub * 256 + wave * 64 + grp) * DD
                   + gl * 4;

    f4 A0 = {0.f, 0.f, 0.f, 0.f}, A1 = A0, A2 = A0, A3 = A0;

    if (b < CACHED_B) {
        atom_loop<false>(p, w0, w1, w2, w3, cb, A0, A1, A2, A3);  // L3-pinned half
    } else {
        atom_loop<true >(p, w0, w1, w2, w3, cb, A0, A1, A2, A3);  // NT stream half
    }

#define XRED(v)                              \
    v.x += __shfl_xor(v.x, 16, 64); v.x += __shfl_xor(v.x, 32, 64); \
    v.y += __shfl_xor(v.y, 16, 64); v.y += __shfl_xor(v.y, 32, 64); \
    v.z += __shfl_xor(v.z, 16, 64); v.z += __shfl_xor(v.z, 32, 64); \
    v.w += __shfl_xor(v.w, 16, 64); v.w += __shfl_xor(v.w, 32, 64);
    XRED(A0) XRED(A1) XRED(A2) XRED(A3)
#undef XRED

    if (grp == 0) {
        *(f4*)&tsh[wave][gl * 4]       = A0;
        *(f4*)&tsh[wave][gl * 4 + 64]  = A1;
        *(f4*)&tsh[wave][gl * 4 + 128] = A2;
        *(f4*)&tsh[wave][gl * 4 + 192] = A3;
    }
    __syncthreads();
    partials[(size_t)blk * DD + tid] =
        tsh[0][tid] + tsh[1][tid] + tsh[2][tid] + tsh[3][tid];
}

// ---------------------------------------------------------------------------
// k_mid: grid (32 b x 16 q), 256 threads.
// ---------------------------------------------------------------------------
__global__ __launch_bounds__(256) void k_mid(const float* __restrict__ partials,
                                             const float* __restrict__ W,
                                             const float* __restrict__ obj,
                                             float* __restrict__ x) {
    int b = blockIdx.x >> 4, q = blockIdx.x & 15;
    int t = threadIdx.x;
    __shared__ float tt[DD];
    __shared__ float so[DD];

    float s = 0.f;
#pragma unroll 8
    for (int i = 0; i < SUBS; ++i) s += partials[((size_t)(b * SUBS + i)) * DD + t];
    tt[t] = s;
    so[t] = obj[(size_t)b * DD + t];
    __syncthreads();

    int kk = t >> 4, cs = t & 15;
    int k  = q * 16 + kk;
    const float4* wr = (const float4*)(W + (size_t)k * DD + cs * 16);
    float p = 0.f, po = 0.f;
#pragma unroll
    for (int ii = 0; ii < 4; ++ii) {
        int i = (ii + cs) & 3;
        float4 a  = wr[i];
        float4 xx = *(const float4*)&tt[cs * 16 + i * 4];
        float4 oo = *(const float4*)&so[cs * 16 + i * 4];
        p  += a.x * xx.x + a.y * xx.y + a.z * xx.z + a.w * xx.w;
        po += a.x * oo.x + a.y * oo.y + a.z * oo.z + a.w * oo.w;
    }
    p  = rowsum16(p);
    po = rowsum16(po);
    if (cs == 0) {
        x[b * 2 * DD + DD + k] = p;   // msg
        x[b * 2 * DD + k]      = po;  // o1
    }
}

// ---------------------------------------------------------------------------
// k_class: grid (4 bg x 63 ch), 256 threads.
// ---------------------------------------------------------------------------
__global__ __launch_bounds__(256) void k_class(const float* __restrict__ x,
                                               const float* __restrict__ CW,
                                               const float* __restrict__ CB,
                                               float* __restrict__ out) {
    int bg = blockIdx.x / 63, ch = blockIdx.x % 63;
    int t = threadIdx.x;
    __shared__ float xs[8][2 * DD];   // 16 KB

    {
        const f4* src = (const f4*)(x + (size_t)bg * 8 * 2 * DD);
        f4* dst = (f4*)&xs[0][0];
#pragma unroll
        for (int i = 0; i < 4; ++i) dst[t + 256 * i] = src[t + 256 * i];
    }
    __syncthreads();

    int cl = t >> 4, seg = t & 15;
    int j = ch * 16 + cl;
    if (j < CC) {
        const f4* cw = (const f4*)(CW + (size_t)j * 2 * DD + seg * 32);
        float p[8];
#pragma unroll
        for (int bb = 0; bb < 8; ++bb) p[bb] = 0.f;
#pragma unroll
        for (int ii = 0; ii < 8; ++ii) {
            int i = (ii + seg) & 7;
            f4 a = cw[i];
#pragma unroll
            for (int bb = 0; bb < 8; ++bb) {
                f4 v = *(const f4*)&xs[bb][seg * 32 + i * 4];
                p[bb] += a.x * v.x + a.y * v.y + a.z * v.z + a.w * v.w;
            }
        }
#pragma unroll
        for (int bb = 0; bb < 8; ++bb) p[bb] = rowsum16(p[bb]);
        if (seg == 0) {
            float cb = CB[j];
            int b0 = bg * 8;
#pragma unroll
            for (int bb = 0; bb < 8; ++bb)
                out[(size_t)(b0 + bb) * CC + j] = p[bb] + cb;
        }
    }
}

// ---------------------------------------------------------------------------
extern "C" void kernel_launch(void* const* d_in, const int* in_sizes, int n_in,
                              void* d_out, int out_size, void* d_ws, size_t ws_size,
                              hipStream_t stream) {
    const float* atom = (const float*)d_in[0];
    const float* obj  = (const float*)d_in[1];
    const float* W    = (const float*)d_in[2];
    const float* A    = (const float*)d_in[3];
    const float* CW   = (const float*)d_in[4];
    const float* CB   = (const float*)d_in[5];
    float* out = (float*)d_out;

    float* ws = (float*)d_ws;
    float* v1       = ws;                        // 256
    float* c        = ws + 256;                  // 32
    float* x        = ws + 512;                  // 32*512 ([o1, msg] per batch)
    float* partials = x + (size_t)BB * 2 * DD;   // 1024*256 (~1 MB)

    hipLaunchKernelGGL(k_prep,  dim3(BB),        dim3(256), 0, stream, W, A, obj, v1, c);
    hipLaunchKernelGGL(k_main,  dim3(BB * SUBS), dim3(256), 0, stream, atom, v1, c, partials);
    hipLaunchKernelGGL(k_mid,   dim3(BB * 16),   dim3(256), 0, stream, partials, W, obj, x);
    hipLaunchKernelGGL(k_class, dim3(4 * 63),    dim3(256), 0, stream, x, CW, CB, out);
}